// Round 1
// baseline (378.092 us; speedup 1.0000x reference)
//
#include <hip/hip_runtime.h>
#include <hip/hip_bf16.h>

#define D_MODEL 1536
#define NEXP    64
#define D_HID   512
#define NTOK    4096
#define NSLOT   (NTOK * 2)

typedef __attribute__((ext_vector_type(8))) short short8;
typedef __attribute__((ext_vector_type(4))) float f32x4;

__device__ __forceinline__ unsigned short f2bf(float f) {
  unsigned u = __builtin_bit_cast(unsigned, f);
  u += 0x7FFFu + ((u >> 16) & 1u);       // round-to-nearest-even
  return (unsigned short)(u >> 16);
}

// ---------------- utility kernels ----------------

__global__ void zero_out_kernel(float* __restrict__ out) {
  long i = (long)(blockIdx.x * 256 + threadIdx.x) * 4;
  *(float4*)(out + i) = make_float4(0.f, 0.f, 0.f, 0.f);
}

__global__ void zero_small_kernel(int* __restrict__ counts) {
  counts[threadIdx.x] = 0;
}

__global__ void cvt_kernel(const float* __restrict__ x, unsigned short* __restrict__ xb) {
  long i = (long)(blockIdx.x * 256 + threadIdx.x) * 8;
  float4 a = *(const float4*)(x + i);
  float4 b = *(const float4*)(x + i + 4);
  uint4 p;
  p.x = (unsigned)f2bf(a.x) | ((unsigned)f2bf(a.y) << 16);
  p.y = (unsigned)f2bf(a.z) | ((unsigned)f2bf(a.w) << 16);
  p.z = (unsigned)f2bf(b.x) | ((unsigned)f2bf(b.y) << 16);
  p.w = (unsigned)f2bf(b.z) | ((unsigned)f2bf(b.w) << 16);
  *(uint4*)(xb + i) = p;
}

// ---------------- router (fp32, LDS-tiled) ----------------
// 16 tokens per block, 64 experts per lane; 4-bucket fp32 accumulation.

__global__ __launch_bounds__(256) void router_kernel(const float* __restrict__ x,
    const float* __restrict__ Wr, int* __restrict__ topidx, float* __restrict__ topw,
    int* __restrict__ counts)
{
  __shared__ float xs[16][32];
  __shared__ float wst[32][64];
  const int tid  = threadIdx.x;
  const int lane = tid & 63;
  const int wv   = tid >> 6;
  const int t0   = blockIdx.x * 16;

  float acc[4][4];
  #pragma unroll
  for (int i = 0; i < 4; ++i)
    #pragma unroll
    for (int j = 0; j < 4; ++j) acc[i][j] = 0.f;

  for (int k0 = 0; k0 < D_MODEL; k0 += 32) {
    __syncthreads();
    {
      int r = tid >> 5, c = tid & 31;
      xs[r][c]     = x[(long)(t0 + r) * D_MODEL + k0 + c];
      xs[r + 8][c] = x[(long)(t0 + r + 8) * D_MODEL + k0 + c];
    }
    {
      int e = tid >> 2, q = tid & 3;
      const float* wp = Wr + (long)e * D_MODEL + k0 + q * 8;
      float4 v0 = *(const float4*)wp;
      float4 v1 = *(const float4*)(wp + 4);
      int kk = q * 8;
      wst[kk + 0][e] = v0.x; wst[kk + 1][e] = v0.y; wst[kk + 2][e] = v0.z; wst[kk + 3][e] = v0.w;
      wst[kk + 4][e] = v1.x; wst[kk + 5][e] = v1.y; wst[kk + 6][e] = v1.z; wst[kk + 7][e] = v1.w;
    }
    __syncthreads();
    #pragma unroll
    for (int k = 0; k < 32; k += 4) {
      #pragma unroll
      for (int kb = 0; kb < 4; ++kb) {
        float wvv = wst[k + kb][lane];
        #pragma unroll
        for (int i = 0; i < 4; ++i)
          acc[i][kb] = fmaf(xs[wv * 4 + i][k + kb], wvv, acc[i][kb]);
      }
    }
  }
  float lg[4];
  #pragma unroll
  for (int i = 0; i < 4; ++i) lg[i] = (acc[i][0] + acc[i][1]) + (acc[i][2] + acc[i][3]);

  for (int i = 0; i < 4; ++i) {
    float v = lg[i];
    float v0 = v; int e0 = lane;
    #pragma unroll
    for (int off = 32; off > 0; off >>= 1) {
      float ov = __shfl_xor(v0, off);
      int   oe = __shfl_xor(e0, off);
      if (ov > v0 || (ov == v0 && oe < e0)) { v0 = ov; e0 = oe; }
    }
    float v1 = (lane == e0) ? -3.0e38f : v;
    int e1 = lane;
    #pragma unroll
    for (int off = 32; off > 0; off >>= 1) {
      float ov = __shfl_xor(v1, off);
      int   oe = __shfl_xor(e1, off);
      if (ov > v1 || (ov == v1 && oe < e1)) { v1 = ov; e1 = oe; }
    }
    if (lane == 0) {
      int t = t0 + wv * 4 + i;
      float w0 = 1.f / (1.f + expf(v1 - v0));
      topidx[t * 2]     = e0;
      topidx[t * 2 + 1] = e1;
      topw[t * 2]       = w0;
      topw[t * 2 + 1]   = 1.f - w0;
      atomicAdd(&counts[e0], 1);
      atomicAdd(&counts[e1], 1);
    }
  }
}

// ---------------- scan + scatter ----------------

__global__ void scan_kernel(const int* __restrict__ counts, int* __restrict__ offs,
                            int* __restrict__ tilepfx, int* __restrict__ cursor)
{
  int e = threadIdx.x;   // 64 threads
  int c = counts[e];
  int xx = c;
  #pragma unroll
  for (int off = 1; off < 64; off <<= 1) {
    int y = __shfl_up(xx, off);
    if (e >= off) xx += y;
  }
  offs[e + 1] = xx;
  int tl = (c + 63) >> 6;
  int tx = tl;
  #pragma unroll
  for (int off = 1; off < 64; off <<= 1) {
    int y = __shfl_up(tx, off);
    if (e >= off) tx += y;
  }
  tilepfx[e + 1] = tx;
  if (e == 0) { offs[0] = 0; tilepfx[0] = 0; }
  cursor[e] = 0;
}

__global__ void scatter_kernel(const int* __restrict__ topidx, const float* __restrict__ topw,
    const int* __restrict__ offs, int* __restrict__ cursor,
    int* __restrict__ perm, float* __restrict__ wgt)
{
  int t = blockIdx.x * blockDim.x + threadIdx.x;
  if (t >= NTOK) return;
  #pragma unroll
  for (int k = 0; k < 2; ++k) {
    int e = topidx[t * 2 + k];
    float w = topw[t * 2 + k];
    int pos = atomicAdd(&cursor[e], 1);
    int slot = offs[e] + pos;
    perm[slot] = t;
    wgt[slot] = w;
  }
}

// ---------------- grouped FFN GEMMs ----------------

__device__ __forceinline__ void find_tile(const int* __restrict__ tilepfx, int bid,
                                          int& e, int& tloc) {
  e = 0;
  while (bid >= tilepfx[e + 1]) ++e;
  tloc = bid - tilepfx[e];
}

__global__ __launch_bounds__(256) void ffn1_kernel(
    const unsigned short* __restrict__ xb, const float* __restrict__ W1,
    const int* __restrict__ tilepfx, const int* __restrict__ offs,
    const int* __restrict__ counts, const int* __restrict__ perm,
    const float* __restrict__ wgt, unsigned short* __restrict__ hbuf)
{
  const int bid = blockIdx.x;
  if (bid >= tilepfx[NEXP]) return;
  int e, tloc; find_tile(tilepfx, bid, e, tloc);
  const int nc = blockIdx.y;                   // 0..1 : 256-col chunk of H
  const int tileStart = offs[e] + tloc * 64;
  const int mcnt = min(64, counts[e] - tloc * 64);

  __shared__ unsigned short As[64 * 64];
  __shared__ unsigned short Bs[256 * 64];

  const int tid = threadIdx.x;
  const int lane = tid & 63;
  const int wv = tid >> 6;

  f32x4 acc[4][4];
  #pragma unroll
  for (int i = 0; i < 4; ++i)
    #pragma unroll
    for (int j = 0; j < 4; ++j) acc[i][j] = (f32x4)0.f;

  const float* Bbase = W1 + (long)e * (D_HID * D_MODEL) + (long)(nc * 256) * D_MODEL;

  for (int k0 = 0; k0 < D_MODEL; k0 += 64) {
    __syncthreads();
    // stage A: 64 rows x 64 k (bf16, 16B-slot XOR swizzle)
    #pragma unroll
    for (int p = 0; p < 2; ++p) {
      int flat = p * 256 + tid;
      int r = flat >> 3, s = flat & 7;
      uint4 v = make_uint4(0u, 0u, 0u, 0u);
      if (r < mcnt) {
        int t = perm[tileStart + r];
        v = *(const uint4*)(xb + (long)t * D_MODEL + k0 + s * 8);
      }
      int phys = s ^ (r & 7);
      *(uint4*)(As + r * 64 + phys * 8) = v;
    }
    // stage B: 256 rows x 64 k, fp32 -> bf16
    #pragma unroll 4
    for (int j = 0; j < 16; ++j) {
      int flat = j * 256 + tid;
      int r = flat >> 4, q = flat & 15;
      const float* p4 = Bbase + (long)r * D_MODEL + k0 + q * 4;
      float4 v = *(const float4*)p4;
      unsigned lo = (unsigned)f2bf(v.x) | ((unsigned)f2bf(v.y) << 16);
      unsigned hi = (unsigned)f2bf(v.z) | ((unsigned)f2bf(v.w) << 16);
      int s = q >> 1, hf = q & 1;
      int phys = s ^ (r & 7);
      *(uint2*)(Bs + r * 64 + phys * 8 + hf * 4) = make_uint2(lo, hi);
    }
    __syncthreads();
    #pragma unroll
    for (int ks = 0; ks < 2; ++ks) {
      short8 a[4], b[4];
      #pragma unroll
      for (int mi = 0; mi < 4; ++mi) {
        int r = mi * 16 + (lane & 15);
        int slot = ks * 4 + (lane >> 4);
        int phys = slot ^ (r & 7);
        a[mi] = *(const short8*)(As + r * 64 + phys * 8);
      }
      #pragma unroll
      for (int ni = 0; ni < 4; ++ni) {
        int n = wv * 64 + ni * 16 + (lane & 15);
        int slot = ks * 4 + (lane >> 4);
        int phys = slot ^ (n & 7);
        b[ni] = *(const short8*)(Bs + n * 64 + phys * 8);
      }
      #pragma unroll
      for (int mi = 0; mi < 4; ++mi)
        #pragma unroll
        for (int ni = 0; ni < 4; ++ni)
          acc[mi][ni] = __builtin_amdgcn_mfma_f32_16x16x32_bf16(a[mi], b[ni], acc[mi][ni], 0, 0, 0);
    }
  }
  // epilogue: SiLU * gate weight -> bf16 hbuf
  const int rsub = (lane >> 4) * 4;
  const int csub = lane & 15;
  #pragma unroll
  for (int mi = 0; mi < 4; ++mi) {
    #pragma unroll
    for (int rg = 0; rg < 4; ++rg) {
      int r = mi * 16 + rsub + rg;
      if (r < mcnt) {
        float wt = wgt[tileStart + r];
        unsigned short* hrow = hbuf + (long)(tileStart + r) * D_HID + nc * 256 + wv * 64 + csub;
        #pragma unroll
        for (int ni = 0; ni < 4; ++ni) {
          float v = acc[mi][ni][rg];
          float sv = v / (1.f + __expf(-v)) * wt;
          hrow[ni * 16] = f2bf(sv);
        }
      }
    }
  }
}

__global__ __launch_bounds__(256) void ffn2_kernel(
    const unsigned short* __restrict__ hbuf, const float* __restrict__ W2,
    const int* __restrict__ tilepfx, const int* __restrict__ offs,
    const int* __restrict__ counts, const int* __restrict__ perm,
    float* __restrict__ out)
{
  const int bid = blockIdx.x;
  if (bid >= tilepfx[NEXP]) return;
  int e, tloc; find_tile(tilepfx, bid, e, tloc);
  const int nc = blockIdx.y;                   // 0..5 : 256-col chunk of D_MODEL
  const int tileStart = offs[e] + tloc * 64;
  const int mcnt = min(64, counts[e] - tloc * 64);

  __shared__ unsigned short As[64 * 64];
  __shared__ unsigned short Bs[256 * 64];

  const int tid = threadIdx.x;
  const int lane = tid & 63;
  const int wv = tid >> 6;

  f32x4 acc[4][4];
  #pragma unroll
  for (int i = 0; i < 4; ++i)
    #pragma unroll
    for (int j = 0; j < 4; ++j) acc[i][j] = (f32x4)0.f;

  const float* Bbase = W2 + (long)e * (D_MODEL * D_HID) + (long)(nc * 256) * D_HID;

  for (int k0 = 0; k0 < D_HID; k0 += 64) {
    __syncthreads();
    #pragma unroll
    for (int p = 0; p < 2; ++p) {
      int flat = p * 256 + tid;
      int r = flat >> 3, s = flat & 7;
      uint4 v = make_uint4(0u, 0u, 0u, 0u);
      if (r < mcnt)
        v = *(const uint4*)(hbuf + (long)(tileStart + r) * D_HID + k0 + s * 8);
      int phys = s ^ (r & 7);
      *(uint4*)(As + r * 64 + phys * 8) = v;
    }
    #pragma unroll 4
    for (int j = 0; j < 16; ++j) {
      int flat = j * 256 + tid;
      int r = flat >> 4, q = flat & 15;
      const float* p4 = Bbase + (long)r * D_HID + k0 + q * 4;
      float4 v = *(const float4*)p4;
      unsigned lo = (unsigned)f2bf(v.x) | ((unsigned)f2bf(v.y) << 16);
      unsigned hi = (unsigned)f2bf(v.z) | ((unsigned)f2bf(v.w) << 16);
      int s = q >> 1, hf = q & 1;
      int phys = s ^ (r & 7);
      *(uint2*)(Bs + r * 64 + phys * 8 + hf * 4) = make_uint2(lo, hi);
    }
    __syncthreads();
    #pragma unroll
    for (int ks = 0; ks < 2; ++ks) {
      short8 a[4], b[4];
      #pragma unroll
      for (int mi = 0; mi < 4; ++mi) {
        int r = mi * 16 + (lane & 15);
        int slot = ks * 4 + (lane >> 4);
        int phys = slot ^ (r & 7);
        a[mi] = *(const short8*)(As + r * 64 + phys * 8);
      }
      #pragma unroll
      for (int ni = 0; ni < 4; ++ni) {
        int n = wv * 64 + ni * 16 + (lane & 15);
        int slot = ks * 4 + (lane >> 4);
        int phys = slot ^ (n & 7);
        b[ni] = *(const short8*)(Bs + n * 64 + phys * 8);
      }
      #pragma unroll
      for (int mi = 0; mi < 4; ++mi)
        #pragma unroll
        for (int ni = 0; ni < 4; ++ni)
          acc[mi][ni] = __builtin_amdgcn_mfma_f32_16x16x32_bf16(a[mi], b[ni], acc[mi][ni], 0, 0, 0);
    }
  }
  // epilogue: atomic accumulate into pre-LN out
  const int rsub = (lane >> 4) * 4;
  const int csub = lane & 15;
  #pragma unroll
  for (int mi = 0; mi < 4; ++mi) {
    #pragma unroll
    for (int rg = 0; rg < 4; ++rg) {
      int r = mi * 16 + rsub + rg;
      if (r < mcnt) {
        int t = perm[tileStart + r];
        float* orow = out + (long)t * D_MODEL + nc * 256 + wv * 64 + csub;
        #pragma unroll
        for (int ni = 0; ni < 4; ++ni)
          atomicAdd(orow + ni * 16, acc[mi][ni][rg]);
      }
    }
  }
}

// ---------------- LayerNorm (in-place on d_out) ----------------

__global__ __launch_bounds__(192) void ln_kernel(float* __restrict__ out,
    const float* __restrict__ gamma, const float* __restrict__ beta)
{
  const int tid = threadIdx.x;
  float* row = out + (long)blockIdx.x * D_MODEL;
  float4 a = *(float4*)(row + tid * 8);
  float4 b = *(float4*)(row + tid * 8 + 4);
  float s  = ((a.x + a.y) + (a.z + a.w)) + ((b.x + b.y) + (b.z + b.w));
  float sq = ((a.x * a.x + a.y * a.y) + (a.z * a.z + a.w * a.w)) +
             ((b.x * b.x + b.y * b.y) + (b.z * b.z + b.w * b.w));
  #pragma unroll
  for (int off = 32; off > 0; off >>= 1) {
    s  += __shfl_xor(s, off);
    sq += __shfl_xor(sq, off);
  }
  __shared__ float ss[3], sqs[3];
  int wv = tid >> 6;
  if ((tid & 63) == 0) { ss[wv] = s; sqs[wv] = sq; }
  __syncthreads();
  s  = ss[0] + ss[1] + ss[2];
  sq = sqs[0] + sqs[1] + sqs[2];
  const float inv = 1.f / (float)D_MODEL;
  float mu  = s * inv;
  float var = sq * inv - mu * mu;
  float rs  = 1.f / sqrtf(var + 1e-5f);
  float4 g1 = *(const float4*)(gamma + tid * 8);
  float4 g2 = *(const float4*)(gamma + tid * 8 + 4);
  float4 b1 = *(const float4*)(beta + tid * 8);
  float4 b2 = *(const float4*)(beta + tid * 8 + 4);
  a.x = (a.x - mu) * rs * g1.x + b1.x;
  a.y = (a.y - mu) * rs * g1.y + b1.y;
  a.z = (a.z - mu) * rs * g1.z + b1.z;
  a.w = (a.w - mu) * rs * g1.w + b1.w;
  b.x = (b.x - mu) * rs * g2.x + b2.x;
  b.y = (b.y - mu) * rs * g2.y + b2.y;
  b.z = (b.z - mu) * rs * g2.z + b2.z;
  b.w = (b.w - mu) * rs * g2.w + b2.w;
  *(float4*)(row + tid * 8)     = a;
  *(float4*)(row + tid * 8 + 4) = b;
}

// ---------------- launch ----------------

extern "C" void kernel_launch(void* const* d_in, const int* in_sizes, int n_in,
                              void* d_out, int out_size, void* d_ws, size_t ws_size,
                              hipStream_t stream) {
  const float* x     = (const float*)d_in[0];
  const float* Wr    = (const float*)d_in[1];
  const float* W1    = (const float*)d_in[2];
  const float* W2    = (const float*)d_in[3];
  const float* gamma = (const float*)d_in[4];
  const float* beta  = (const float*)d_in[5];
  float* out = (float*)d_out;

  char* ws = (char*)d_ws;
  unsigned short* xb    = (unsigned short*)(ws + 0);          // 12,582,912 B
  unsigned short* hbuf  = (unsigned short*)(ws + 12582912);   //  8,388,608 B
  int*   topidx = (int*)  (ws + 20971520);                    //     32,768 B
  float* topw   = (float*)(ws + 21004288);                    //     32,768 B
  int*   counts = (int*)  (ws + 21037056);                    //        256 B
  int*   cursor = (int*)  (ws + 21037312);                    //        256 B
  int*   offs   = (int*)  (ws + 21037568);                    //        512 B
  int*   tilepfx= (int*)  (ws + 21038080);                    //        512 B
  int*   perm   = (int*)  (ws + 21038592);                    //     32,768 B
  float* wgt    = (float*)(ws + 21071360);                    //     32,768 B

  hipLaunchKernelGGL(zero_out_kernel, dim3((NTOK * D_MODEL) / (256 * 4)), dim3(256), 0, stream, out);
  hipLaunchKernelGGL(zero_small_kernel, dim3(1), dim3(64), 0, stream, counts);
  hipLaunchKernelGGL(cvt_kernel, dim3((NTOK * D_MODEL) / (256 * 8)), dim3(256), 0, stream, x, xb);
  hipLaunchKernelGGL(router_kernel, dim3(NTOK / 16), dim3(256), 0, stream, x, Wr, topidx, topw, counts);
  hipLaunchKernelGGL(scan_kernel, dim3(1), dim3(64), 0, stream, counts, offs, tilepfx, cursor);
  hipLaunchKernelGGL(scatter_kernel, dim3(NTOK / 256), dim3(256), 0, stream, topidx, topw, offs, cursor, perm, wgt);
  hipLaunchKernelGGL(ffn1_kernel, dim3(192, 2), dim3(256), 0, stream, xb, W1, tilepfx, offs, counts, perm, wgt, hbuf);
  hipLaunchKernelGGL(ffn2_kernel, dim3(192, 6), dim3(256), 0, stream, hbuf, W2, tilepfx, offs, counts, perm, out);
  hipLaunchKernelGGL(ln_kernel, dim3(NTOK), dim3(192), 0, stream, out, gamma, beta);
}

// Round 3
// 313.509 us; speedup vs baseline: 1.2060x; 1.2060x over previous
//
#include <hip/hip_runtime.h>
#include <hip/hip_bf16.h>

#define D_MODEL 1536
#define NEXP    64
#define D_HID   512
#define NTOK    4096
#define NSLOT   (NTOK * 2)
#define NK1     (D_MODEL / 64)   // 24
#define NK2     (D_HID / 64)     // 8
#define BUFSZ   (128*64 + 64*64) // elements per LDS buffer

typedef __attribute__((ext_vector_type(8))) short short8;
typedef __attribute__((ext_vector_type(4))) float f32x4;

__device__ __forceinline__ unsigned short f2bf(float f) {
  unsigned u = __builtin_bit_cast(unsigned, f);
  u += 0x7FFFu + ((u >> 16) & 1u);
  return (unsigned short)(u >> 16);
}

__device__ __forceinline__ unsigned pk2(float a, float b) {
  return (unsigned)f2bf(a) | ((unsigned)f2bf(b) << 16);
}

// ---------------- utility kernels ----------------

__global__ void zero_out_kernel(float* __restrict__ out) {
  long i = (long)(blockIdx.x * 256 + threadIdx.x) * 4;
  *(float4*)(out + i) = make_float4(0.f, 0.f, 0.f, 0.f);
}

__global__ void zero_small_kernel(int* __restrict__ counts) {
  counts[threadIdx.x] = 0;
}

__global__ void cvt_kernel(const float* __restrict__ x, unsigned short* __restrict__ xb) {
  long i = (long)(blockIdx.x * 256 + threadIdx.x) * 8;
  float4 a = *(const float4*)(x + i);
  float4 b = *(const float4*)(x + i + 4);
  uint4 p;
  p.x = pk2(a.x, a.y);
  p.y = pk2(a.z, a.w);
  p.z = pk2(b.x, b.y);
  p.w = pk2(b.z, b.w);
  *(uint4*)(xb + i) = p;
}

// ---------------- router (fp32, LDS-tiled) ----------------

__global__ __launch_bounds__(256) void router_kernel(const float* __restrict__ x,
    const float* __restrict__ Wr, int* __restrict__ topidx, float* __restrict__ topw,
    int* __restrict__ counts)
{
  __shared__ float xs[16][32];
  __shared__ float wst[32][64];
  const int tid  = threadIdx.x;
  const int lane = tid & 63;
  const int wv   = tid >> 6;
  const int t0   = blockIdx.x * 16;

  float acc[4][4];
  #pragma unroll
  for (int i = 0; i < 4; ++i)
    #pragma unroll
    for (int j = 0; j < 4; ++j) acc[i][j] = 0.f;

  for (int k0 = 0; k0 < D_MODEL; k0 += 32) {
    __syncthreads();
    {
      int r = tid >> 5, c = tid & 31;
      xs[r][c]     = x[(long)(t0 + r) * D_MODEL + k0 + c];
      xs[r + 8][c] = x[(long)(t0 + r + 8) * D_MODEL + k0 + c];
    }
    {
      int e = tid >> 2, q = tid & 3;
      const float* wp = Wr + (long)e * D_MODEL + k0 + q * 8;
      float4 v0 = *(const float4*)wp;
      float4 v1 = *(const float4*)(wp + 4);
      int kk = q * 8;
      wst[kk + 0][e] = v0.x; wst[kk + 1][e] = v0.y; wst[kk + 2][e] = v0.z; wst[kk + 3][e] = v0.w;
      wst[kk + 4][e] = v1.x; wst[kk + 5][e] = v1.y; wst[kk + 6][e] = v1.z; wst[kk + 7][e] = v1.w;
    }
    __syncthreads();
    #pragma unroll
    for (int k = 0; k < 32; k += 4) {
      #pragma unroll
      for (int kb = 0; kb < 4; ++kb) {
        float wvv = wst[k + kb][lane];
        #pragma unroll
        for (int i = 0; i < 4; ++i)
          acc[i][kb] = fmaf(xs[wv * 4 + i][k + kb], wvv, acc[i][kb]);
      }
    }
  }
  float lg[4];
  #pragma unroll
  for (int i = 0; i < 4; ++i) lg[i] = (acc[i][0] + acc[i][1]) + (acc[i][2] + acc[i][3]);

  for (int i = 0; i < 4; ++i) {
    float v = lg[i];
    float v0 = v; int e0 = lane;
    #pragma unroll
    for (int off = 32; off > 0; off >>= 1) {
      float ov = __shfl_xor(v0, off);
      int   oe = __shfl_xor(e0, off);
      if (ov > v0 || (ov == v0 && oe < e0)) { v0 = ov; e0 = oe; }
    }
    float v1 = (lane == e0) ? -3.0e38f : v;
    int e1 = lane;
    #pragma unroll
    for (int off = 32; off > 0; off >>= 1) {
      float ov = __shfl_xor(v1, off);
      int   oe = __shfl_xor(e1, off);
      if (ov > v1 || (ov == v1 && oe < e1)) { v1 = ov; e1 = oe; }
    }
    if (lane == 0) {
      int t = t0 + wv * 4 + i;
      float w0 = 1.f / (1.f + expf(v1 - v0));
      topidx[t * 2]     = e0;
      topidx[t * 2 + 1] = e1;
      topw[t * 2]       = w0;
      topw[t * 2 + 1]   = 1.f - w0;
      atomicAdd(&counts[e0], 1);
      atomicAdd(&counts[e1], 1);
    }
  }
}

// ---------------- scan + scatter ----------------

__global__ void scan_kernel(const int* __restrict__ counts, int* __restrict__ offs,
                            int* __restrict__ tile_e, int* __restrict__ tile_t,
                            int* __restrict__ tilecnt, int* __restrict__ cursor)
{
  int e = threadIdx.x;   // 64 threads
  int c = counts[e];
  int xx = c;
  #pragma unroll
  for (int off = 1; off < 64; off <<= 1) {
    int y = __shfl_up(xx, off);
    if (e >= off) xx += y;
  }
  offs[e + 1] = xx;
  if (e == 0) offs[0] = 0;
  int tl = (c + 127) >> 7;          // 128-token tiles
  int tx = tl;
  #pragma unroll
  for (int off = 1; off < 64; off <<= 1) {
    int y = __shfl_up(tx, off);
    if (e >= off) tx += y;
  }
  int tstart = tx - tl;
  for (int i = 0; i < tl; ++i) { tile_e[tstart + i] = e; tile_t[tstart + i] = i; }
  if (e == 63) tilecnt[0] = tx;
  cursor[e] = 0;
}

__global__ void scatter_kernel(const int* __restrict__ topidx, const float* __restrict__ topw,
    const int* __restrict__ offs, int* __restrict__ cursor,
    int* __restrict__ perm, float* __restrict__ wgt)
{
  int t = blockIdx.x * blockDim.x + threadIdx.x;
  if (t >= NTOK) return;
  #pragma unroll
  for (int k = 0; k < 2; ++k) {
    int e = topidx[t * 2 + k];
    float w = topw[t * 2 + k];
    int pos = atomicAdd(&cursor[e], 1);
    int slot = offs[e] + pos;
    perm[slot] = t;
    wgt[slot] = w;
  }
}

// ---------------- grouped FFN GEMMs (M=128, N-chunk=64, dbuf pipeline) ----------------

__global__ __launch_bounds__(256) void ffn1_kernel(
    const unsigned short* __restrict__ xb, const float* __restrict__ W1,
    const int* __restrict__ tile_e, const int* __restrict__ tile_t,
    const int* __restrict__ tilecnt, const int* __restrict__ offs,
    const int* __restrict__ counts, const int* __restrict__ perm,
    const float* __restrict__ wgt, unsigned short* __restrict__ hbuf)
{
  if (blockIdx.x >= tilecnt[0]) return;
  const int e    = tile_e[blockIdx.x];
  const int tloc = tile_t[blockIdx.x];
  const int nc   = blockIdx.y;                  // 0..7 : 64-col chunk of D_HID
  const int tileStart = offs[e] + tloc * 128;
  const int mcnt = min(128, counts[e] - tloc * 128);

  __shared__ unsigned short lds[2 * BUFSZ];

  const int tid = threadIdx.x;
  const int lane = tid & 63;
  const int wv = tid >> 6;
  const int wm = wv >> 1, wn = wv & 1;

  // A staging roles: 4 rows/thread (p*32 + tid>>3), 16B slot tid&7
  const int sA = tid & 7;
  const int rA = tid >> 3;
  const unsigned short* aptr[4];
  #pragma unroll
  for (int p = 0; p < 4; ++p) {
    int pr = p * 32 + rA;
    aptr[p] = (pr < mcnt) ? xb + (long)perm[tileStart + pr] * D_MODEL + sA * 8 : nullptr;
  }
  // B staging roles: 4 rows/thread (p*16 + tid>>4), float4 slot tid&15
  const int qB = tid & 15;
  const int rB = tid >> 4;
  const float* bptr[4];
  #pragma unroll
  for (int p = 0; p < 4; ++p)
    bptr[p] = W1 + ((long)e * D_HID + nc * 64 + p * 16 + rB) * D_MODEL + qB * 4;

  // fragment addresses
  int arow[4], brow[2];
  int physA[2][4], physB[2][2];
  #pragma unroll
  for (int mi = 0; mi < 4; ++mi) {
    arow[mi] = wm * 64 + mi * 16 + (lane & 15);
    #pragma unroll
    for (int ks = 0; ks < 2; ++ks)
      physA[ks][mi] = (ks * 4 + (lane >> 4)) ^ (arow[mi] & 7);
  }
  #pragma unroll
  for (int ni = 0; ni < 2; ++ni) {
    brow[ni] = wn * 32 + ni * 16 + (lane & 15);
    #pragma unroll
    for (int ks = 0; ks < 2; ++ks)
      physB[ks][ni] = (ks * 4 + (lane >> 4)) ^ (brow[ni] & 7);
  }

  f32x4 acc[4][2];
  #pragma unroll
  for (int i = 0; i < 4; ++i)
    #pragma unroll
    for (int j = 0; j < 2; ++j) acc[i][j] = (f32x4)0.f;

  uint4 areg[4]; float4 breg[4];

  auto LOAD = [&](int k0) {
    #pragma unroll
    for (int p = 0; p < 4; ++p)
      areg[p] = aptr[p] ? *(const uint4*)(aptr[p] + k0) : make_uint4(0u, 0u, 0u, 0u);
    #pragma unroll
    for (int p = 0; p < 4; ++p)
      breg[p] = *(const float4*)(bptr[p] + k0);
  };
  auto WRITE = [&](int b) {
    unsigned short* A_ = lds + b * BUFSZ;
    unsigned short* B_ = A_ + 128 * 64;
    #pragma unroll
    for (int p = 0; p < 4; ++p) {
      int pr = p * 32 + rA;
      *(uint4*)(A_ + pr * 64 + (sA ^ (pr & 7)) * 8) = areg[p];
    }
    #pragma unroll
    for (int p = 0; p < 4; ++p) {
      int rr = p * 16 + rB;
      unsigned lo = pk2(breg[p].x, breg[p].y);
      unsigned hi = pk2(breg[p].z, breg[p].w);
      int phys = (qB >> 1) ^ (rr & 7);
      *(uint2*)(B_ + rr * 64 + phys * 8 + (qB & 1) * 4) = make_uint2(lo, hi);
    }
  };
  auto COMPUTE = [&](int b) {
    const unsigned short* A_ = lds + b * BUFSZ;
    const unsigned short* B_ = A_ + 128 * 64;
    #pragma unroll
    for (int ks = 0; ks < 2; ++ks) {
      short8 a[4], bb[2];
      #pragma unroll
      for (int mi = 0; mi < 4; ++mi)
        a[mi] = *(const short8*)(A_ + arow[mi] * 64 + physA[ks][mi] * 8);
      #pragma unroll
      for (int ni = 0; ni < 2; ++ni)
        bb[ni] = *(const short8*)(B_ + brow[ni] * 64 + physB[ks][ni] * 8);
      #pragma unroll
      for (int mi = 0; mi < 4; ++mi)
        #pragma unroll
        for (int ni = 0; ni < 2; ++ni)
          acc[mi][ni] = __builtin_amdgcn_mfma_f32_16x16x32_bf16(a[mi], bb[ni], acc[mi][ni], 0, 0, 0);
    }
  };

  LOAD(0);
  WRITE(0);
  __syncthreads();
  #pragma unroll 1
  for (int t = 0; t < NK1; ++t) {
    if (t + 1 < NK1) LOAD((t + 1) * 64);
    COMPUTE(t & 1);
    if (t + 1 < NK1) {
      WRITE((t + 1) & 1);
      __syncthreads();
    }
  }

  // epilogue: SiLU * gate -> bf16 hbuf
  const int rsub = (lane >> 4) * 4;
  const int csub = lane & 15;
  #pragma unroll
  for (int mi = 0; mi < 4; ++mi) {
    #pragma unroll
    for (int rg = 0; rg < 4; ++rg) {
      int r = wm * 64 + mi * 16 + rsub + rg;
      if (r < mcnt) {
        float wt = wgt[tileStart + r];
        unsigned short* hrow = hbuf + (long)(tileStart + r) * D_HID + nc * 64 + wn * 32 + csub;
        #pragma unroll
        for (int ni = 0; ni < 2; ++ni) {
          float v = acc[mi][ni][rg];
          float sv = v / (1.f + __expf(-v)) * wt;
          hrow[ni * 16] = f2bf(sv);
        }
      }
    }
  }
}

__global__ __launch_bounds__(256) void ffn2_kernel(
    const unsigned short* __restrict__ hbuf, const float* __restrict__ W2,
    const int* __restrict__ tile_e, const int* __restrict__ tile_t,
    const int* __restrict__ tilecnt, const int* __restrict__ offs,
    const int* __restrict__ counts, const int* __restrict__ perm,
    float* __restrict__ out)
{
  if (blockIdx.x >= tilecnt[0]) return;
  const int e    = tile_e[blockIdx.x];
  const int tloc = tile_t[blockIdx.x];
  const int nc   = blockIdx.y;                  // 0..23 : 64-col chunk of D_MODEL
  const int tileStart = offs[e] + tloc * 128;
  const int mcnt = min(128, counts[e] - tloc * 128);

  __shared__ unsigned short lds[2 * BUFSZ];

  const int tid = threadIdx.x;
  const int lane = tid & 63;
  const int wv = tid >> 6;
  const int wm = wv >> 1, wn = wv & 1;

  const int sA = tid & 7;
  const int rA = tid >> 3;
  const unsigned short* aptr[4];
  #pragma unroll
  for (int p = 0; p < 4; ++p) {
    int pr = p * 32 + rA;
    aptr[p] = (pr < mcnt) ? hbuf + (long)(tileStart + pr) * D_HID + sA * 8 : nullptr;
  }
  const int qB = tid & 15;
  const int rB = tid >> 4;
  const float* bptr[4];
  #pragma unroll
  for (int p = 0; p < 4; ++p)
    bptr[p] = W2 + ((long)e * D_MODEL + nc * 64 + p * 16 + rB) * D_HID + qB * 4;

  int arow[4], brow[2];
  int physA[2][4], physB[2][2];
  #pragma unroll
  for (int mi = 0; mi < 4; ++mi) {
    arow[mi] = wm * 64 + mi * 16 + (lane & 15);
    #pragma unroll
    for (int ks = 0; ks < 2; ++ks)
      physA[ks][mi] = (ks * 4 + (lane >> 4)) ^ (arow[mi] & 7);
  }
  #pragma unroll
  for (int ni = 0; ni < 2; ++ni) {
    brow[ni] = wn * 32 + ni * 16 + (lane & 15);
    #pragma unroll
    for (int ks = 0; ks < 2; ++ks)
      physB[ks][ni] = (ks * 4 + (lane >> 4)) ^ (brow[ni] & 7);
  }

  f32x4 acc[4][2];
  #pragma unroll
  for (int i = 0; i < 4; ++i)
    #pragma unroll
    for (int j = 0; j < 2; ++j) acc[i][j] = (f32x4)0.f;

  uint4 areg[4]; float4 breg[4];

  auto LOAD = [&](int k0) {
    #pragma unroll
    for (int p = 0; p < 4; ++p)
      areg[p] = aptr[p] ? *(const uint4*)(aptr[p] + k0) : make_uint4(0u, 0u, 0u, 0u);
    #pragma unroll
    for (int p = 0; p < 4; ++p)
      breg[p] = *(const float4*)(bptr[p] + k0);
  };
  auto WRITE = [&](int b) {
    unsigned short* A_ = lds + b * BUFSZ;
    unsigned short* B_ = A_ + 128 * 64;
    #pragma unroll
    for (int p = 0; p < 4; ++p) {
      int pr = p * 32 + rA;
      *(uint4*)(A_ + pr * 64 + (sA ^ (pr & 7)) * 8) = areg[p];
    }
    #pragma unroll
    for (int p = 0; p < 4; ++p) {
      int rr = p * 16 + rB;
      unsigned lo = pk2(breg[p].x, breg[p].y);
      unsigned hi = pk2(breg[p].z, breg[p].w);
      int phys = (qB >> 1) ^ (rr & 7);
      *(uint2*)(B_ + rr * 64 + phys * 8 + (qB & 1) * 4) = make_uint2(lo, hi);
    }
  };
  auto COMPUTE = [&](int b) {
    const unsigned short* A_ = lds + b * BUFSZ;
    const unsigned short* B_ = A_ + 128 * 64;
    #pragma unroll
    for (int ks = 0; ks < 2; ++ks) {
      short8 a[4], bb[2];
      #pragma unroll
      for (int mi = 0; mi < 4; ++mi)
        a[mi] = *(const short8*)(A_ + arow[mi] * 64 + physA[ks][mi] * 8);
      #pragma unroll
      for (int ni = 0; ni < 2; ++ni)
        bb[ni] = *(const short8*)(B_ + brow[ni] * 64 + physB[ks][ni] * 8);
      #pragma unroll
      for (int mi = 0; mi < 4; ++mi)
        #pragma unroll
        for (int ni = 0; ni < 2; ++ni)
          acc[mi][ni] = __builtin_amdgcn_mfma_f32_16x16x32_bf16(a[mi], bb[ni], acc[mi][ni], 0, 0, 0);
    }
  };

  LOAD(0);
  WRITE(0);
  __syncthreads();
  #pragma unroll 1
  for (int t = 0; t < NK2; ++t) {
    if (t + 1 < NK2) LOAD((t + 1) * 64);
    COMPUTE(t & 1);
    if (t + 1 < NK2) {
      WRITE((t + 1) & 1);
      __syncthreads();
    }
  }

  // epilogue: atomic accumulate into pre-LN out
  const int rsub = (lane >> 4) * 4;
  const int csub = lane & 15;
  #pragma unroll
  for (int mi = 0; mi < 4; ++mi) {
    #pragma unroll
    for (int rg = 0; rg < 4; ++rg) {
      int r = wm * 64 + mi * 16 + rsub + rg;
      if (r < mcnt) {
        int t = perm[tileStart + r];
        float* orow = out + (long)t * D_MODEL + nc * 64 + wn * 32 + csub;
        #pragma unroll
        for (int ni = 0; ni < 2; ++ni)
          atomicAdd(orow + ni * 16, acc[mi][ni][rg]);
      }
    }
  }
}

// ---------------- LayerNorm (in-place on d_out) ----------------

__global__ __launch_bounds__(192) void ln_kernel(float* __restrict__ out,
    const float* __restrict__ gamma, const float* __restrict__ beta)
{
  const int tid = threadIdx.x;
  float* row = out + (long)blockIdx.x * D_MODEL;
  float4 a = *(float4*)(row + tid * 8);
  float4 b = *(float4*)(row + tid * 8 + 4);
  float s  = ((a.x + a.y) + (a.z + a.w)) + ((b.x + b.y) + (b.z + b.w));
  float sq = ((a.x * a.x + a.y * a.y) + (a.z * a.z + a.w * a.w)) +
             ((b.x * b.x + b.y * b.y) + (b.z * b.z + b.w * b.w));
  #pragma unroll
  for (int off = 32; off > 0; off >>= 1) {
    s  += __shfl_xor(s, off);
    sq += __shfl_xor(sq, off);
  }
  __shared__ float ss[3], sqs[3];
  int wv = tid >> 6;
  if ((tid & 63) == 0) { ss[wv] = s; sqs[wv] = sq; }
  __syncthreads();
  s  = ss[0] + ss[1] + ss[2];
  sq = sqs[0] + sqs[1] + sqs[2];
  const float inv = 1.f / (float)D_MODEL;
  float mu  = s * inv;
  float var = sq * inv - mu * mu;
  float rs  = 1.f / sqrtf(var + 1e-5f);
  float4 g1 = *(const float4*)(gamma + tid * 8);
  float4 g2 = *(const float4*)(gamma + tid * 8 + 4);
  float4 b1 = *(const float4*)(beta + tid * 8);
  float4 b2 = *(const float4*)(beta + tid * 8 + 4);
  a.x = (a.x - mu) * rs * g1.x + b1.x;
  a.y = (a.y - mu) * rs * g1.y + b1.y;
  a.z = (a.z - mu) * rs * g1.z + b1.z;
  a.w = (a.w - mu) * rs * g1.w + b1.w;
  b.x = (b.x - mu) * rs * g2.x + b2.x;
  b.y = (b.y - mu) * rs * g2.y + b2.y;
  b.z = (b.z - mu) * rs * g2.z + b2.z;
  b.w = (b.w - mu) * rs * g2.w + b2.w;
  *(float4*)(row + tid * 8)     = a;
  *(float4*)(row + tid * 8 + 4) = b;
}

// ---------------- launch ----------------

extern "C" void kernel_launch(void* const* d_in, const int* in_sizes, int n_in,
                              void* d_out, int out_size, void* d_ws, size_t ws_size,
                              hipStream_t stream) {
  const float* x     = (const float*)d_in[0];
  const float* Wr    = (const float*)d_in[1];
  const float* W1    = (const float*)d_in[2];
  const float* W2    = (const float*)d_in[3];
  const float* gamma = (const float*)d_in[4];
  const float* beta  = (const float*)d_in[5];
  float* out = (float*)d_out;

  char* ws = (char*)d_ws;
  unsigned short* xb    = (unsigned short*)(ws + 0);          // 12,582,912 B
  unsigned short* hbuf  = (unsigned short*)(ws + 12582912);   //  8,388,608 B
  int*   topidx = (int*)  (ws + 20971520);                    //     32,768 B
  float* topw   = (float*)(ws + 21004288);                    //     32,768 B
  int*   counts = (int*)  (ws + 21037056);                    //        256 B
  int*   cursor = (int*)  (ws + 21037312);                    //        256 B
  int*   offs   = (int*)  (ws + 21037568);                    //        512 B
  int*   tile_e = (int*)  (ws + 21038080);                    //        512 B
  int*   tile_t = (int*)  (ws + 21038592);                    //        512 B
  int*   tilecnt= (int*)  (ws + 21039104);                    //          4 B
  int*   perm   = (int*)  (ws + 21039616);                    //     32,768 B
  float* wgt    = (float*)(ws + 21072384);                    //     32,768 B

  hipLaunchKernelGGL(zero_out_kernel, dim3((NTOK * D_MODEL) / (256 * 4)), dim3(256), 0, stream, out);
  hipLaunchKernelGGL(zero_small_kernel, dim3(1), dim3(64), 0, stream, counts);
  hipLaunchKernelGGL(cvt_kernel, dim3((NTOK * D_MODEL) / (256 * 8)), dim3(256), 0, stream, x, xb);
  hipLaunchKernelGGL(router_kernel, dim3(NTOK / 16), dim3(256), 0, stream, x, Wr, topidx, topw, counts);
  hipLaunchKernelGGL(scan_kernel, dim3(1), dim3(64), 0, stream, counts, offs, tile_e, tile_t, tilecnt, cursor);
  hipLaunchKernelGGL(scatter_kernel, dim3(NTOK / 256), dim3(256), 0, stream, topidx, topw, offs, cursor, perm, wgt);
  hipLaunchKernelGGL(ffn1_kernel, dim3(128, 8), dim3(256), 0, stream, xb, W1, tile_e, tile_t, tilecnt, offs, counts, perm, wgt, hbuf);
  hipLaunchKernelGGL(ffn2_kernel, dim3(128, 24), dim3(256), 0, stream, hbuf, W2, tile_e, tile_t, tilecnt, offs, counts, perm, out);
  hipLaunchKernelGGL(ln_kernel, dim3(NTOK), dim3(192), 0, stream, out, gamma, beta);
}

// Round 4
// 272.810 us; speedup vs baseline: 1.3859x; 1.1492x over previous
//
#include <hip/hip_runtime.h>
#include <hip/hip_bf16.h>

#define D_MODEL 1536
#define NEXP    64
#define D_HID   512
#define NTOK    4096
#define NSLOT   (NTOK * 2)
#define NK1     (D_MODEL / 64)   // 24
#define NK2     (D_HID / 64)     // 8
#define MT      192              // packed M rows per block pass
#define LDSA    (MT * 64)        // 12288 elems
#define LDSB    (64 * 64)        // 4096 elems
#define BUF     (LDSA + LDSB)    // 16384 elems -> 32KB per buffer, 64KB dbuf

typedef __attribute__((ext_vector_type(8))) short short8;
typedef __attribute__((ext_vector_type(4))) float f32x4;

__device__ __forceinline__ unsigned short f2bf(float f) {
  unsigned u = __builtin_bit_cast(unsigned, f);
  u += 0x7FFFu + ((u >> 16) & 1u);
  return (unsigned short)(u >> 16);
}

__device__ __forceinline__ unsigned pk2(float a, float b) {
  return (unsigned)f2bf(a) | ((unsigned)f2bf(b) << 16);
}

// ---------------- utility kernels ----------------

__global__ void zero_small_kernel(int* __restrict__ counts) {
  counts[threadIdx.x] = 0;
}

__global__ void cvt_kernel(const float* __restrict__ x, unsigned short* __restrict__ xb) {
  long i = (long)(blockIdx.x * 256 + threadIdx.x) * 8;
  float4 a = *(const float4*)(x + i);
  float4 b = *(const float4*)(x + i + 4);
  uint4 p;
  p.x = pk2(a.x, a.y);
  p.y = pk2(a.z, a.w);
  p.z = pk2(b.x, b.y);
  p.w = pk2(b.z, b.w);
  *(uint4*)(xb + i) = p;
}

// ---------------- router (fp32, LDS-tiled, 8 tokens/block) ----------------

__global__ __launch_bounds__(256) void router_kernel(const float* __restrict__ x,
    const float* __restrict__ Wr, int* __restrict__ topidx, float* __restrict__ topw,
    int* __restrict__ counts)
{
  __shared__ float xs[8][32];
  __shared__ float wst[32][64];
  const int tid  = threadIdx.x;
  const int lane = tid & 63;
  const int wv   = tid >> 6;
  const int t0   = blockIdx.x * 8;

  float acc[2][4];
  #pragma unroll
  for (int i = 0; i < 2; ++i)
    #pragma unroll
    for (int j = 0; j < 4; ++j) acc[i][j] = 0.f;

  for (int k0 = 0; k0 < D_MODEL; k0 += 32) {
    __syncthreads();
    {
      int r = tid >> 5, c = tid & 31;
      xs[r][c] = x[(long)(t0 + r) * D_MODEL + k0 + c];
    }
    {
      int e = tid >> 2, q = tid & 3;
      const float* wp = Wr + (long)e * D_MODEL + k0 + q * 8;
      float4 v0 = *(const float4*)wp;
      float4 v1 = *(const float4*)(wp + 4);
      int kk = q * 8;
      wst[kk + 0][e] = v0.x; wst[kk + 1][e] = v0.y; wst[kk + 2][e] = v0.z; wst[kk + 3][e] = v0.w;
      wst[kk + 4][e] = v1.x; wst[kk + 5][e] = v1.y; wst[kk + 6][e] = v1.z; wst[kk + 7][e] = v1.w;
    }
    __syncthreads();
    #pragma unroll
    for (int k = 0; k < 32; k += 4) {
      #pragma unroll
      for (int kb = 0; kb < 4; ++kb) {
        float wvv = wst[k + kb][lane];
        #pragma unroll
        for (int i = 0; i < 2; ++i)
          acc[i][kb] = fmaf(xs[wv * 2 + i][k + kb], wvv, acc[i][kb]);
      }
    }
  }
  float lg[2];
  #pragma unroll
  for (int i = 0; i < 2; ++i) lg[i] = (acc[i][0] + acc[i][1]) + (acc[i][2] + acc[i][3]);

  for (int i = 0; i < 2; ++i) {
    float v = lg[i];
    float v0 = v; int e0 = lane;
    #pragma unroll
    for (int off = 32; off > 0; off >>= 1) {
      float ov = __shfl_xor(v0, off);
      int   oe = __shfl_xor(e0, off);
      if (ov > v0 || (ov == v0 && oe < e0)) { v0 = ov; e0 = oe; }
    }
    float v1 = (lane == e0) ? -3.0e38f : v;
    int e1 = lane;
    #pragma unroll
    for (int off = 32; off > 0; off >>= 1) {
      float ov = __shfl_xor(v1, off);
      int   oe = __shfl_xor(e1, off);
      if (ov > v1 || (ov == v1 && oe < e1)) { v1 = ov; e1 = oe; }
    }
    if (lane == 0) {
      int t = t0 + wv * 2 + i;
      float w0 = 1.f / (1.f + expf(v1 - v0));
      topidx[t * 2]     = e0;
      topidx[t * 2 + 1] = e1;
      topw[t * 2]       = w0;
      topw[t * 2 + 1]   = 1.f - w0;
      atomicAdd(&counts[e0], 1);
      atomicAdd(&counts[e1], 1);
    }
  }
}

// ---------------- scan + scatter ----------------

__global__ void scan_kernel(const int* __restrict__ counts, int* __restrict__ offs,
                            int* __restrict__ cursor)
{
  int e = threadIdx.x;   // 64 threads
  int c = counts[e];
  int xx = c;
  #pragma unroll
  for (int off = 1; off < 64; off <<= 1) {
    int y = __shfl_up(xx, off);
    if (e >= off) xx += y;
  }
  offs[e + 1] = xx;
  if (e == 0) offs[0] = 0;
  cursor[e] = 0;
}

__global__ void scatter_kernel(const int* __restrict__ topidx, const float* __restrict__ topw,
    const int* __restrict__ offs, int* __restrict__ cursor,
    int* __restrict__ perm, float* __restrict__ wgt, int* __restrict__ tok2slot)
{
  int t = blockIdx.x * blockDim.x + threadIdx.x;
  if (t >= NTOK) return;
  #pragma unroll
  for (int k = 0; k < 2; ++k) {
    int e = topidx[t * 2 + k];
    float w = topw[t * 2 + k];
    int pos = atomicAdd(&cursor[e], 1);
    int slot = offs[e] + pos;
    perm[slot] = t;
    wgt[slot] = w;
    tok2slot[t * 2 + k] = slot;
  }
}

// ---------------- grouped FFN GEMMs (block = expert x n-chunk, M packed to 192) ----------------

__global__ __launch_bounds__(256) void ffn1_kernel(
    const unsigned short* __restrict__ xb, const float* __restrict__ W1,
    const int* __restrict__ offs, const int* __restrict__ perm,
    const float* __restrict__ wgt, unsigned short* __restrict__ hbuf)
{
  const int e  = blockIdx.x;
  const int nc = blockIdx.y;                  // 0..7 : 64-col chunk of D_HID
  const int cnt = offs[e + 1] - offs[e];
  if (cnt == 0) return;

  __shared__ unsigned short lds[2 * BUF];

  const int tid = threadIdx.x;
  const int lane = tid & 63;
  const int wv = tid >> 6;

  // B staging roles
  const int qB = tid & 15;
  const int rB = tid >> 4;
  const float* bptr[4];
  #pragma unroll
  for (int p = 0; p < 4; ++p)
    bptr[p] = W1 + ((long)e * D_HID + nc * 64 + p * 16 + rB) * D_MODEL + qB * 4;

  // A staging roles
  const int sA = tid & 7;
  const int rA = tid >> 3;

  // fragment addresses
  int arow[3], brow[4];
  int physA[2][3], physB[2][4];
  #pragma unroll
  for (int mi = 0; mi < 3; ++mi) {
    arow[mi] = wv * 48 + mi * 16 + (lane & 15);
    #pragma unroll
    for (int ks = 0; ks < 2; ++ks)
      physA[ks][mi] = (ks * 4 + (lane >> 4)) ^ (arow[mi] & 7);
  }
  #pragma unroll
  for (int ni = 0; ni < 4; ++ni) {
    brow[ni] = ni * 16 + (lane & 15);
    #pragma unroll
    for (int ks = 0; ks < 2; ++ks)
      physB[ks][ni] = (ks * 4 + (lane >> 4)) ^ (brow[ni] & 7);
  }

  for (int m0 = 0; m0 < cnt; m0 += MT) {
    const int base = offs[e] + m0;
    const int mcnt = min(MT, cnt - m0);

    const unsigned short* aptr[6];
    #pragma unroll
    for (int p = 0; p < 6; ++p) {
      int pr = p * 32 + rA;
      aptr[p] = (pr < mcnt) ? xb + (long)perm[base + pr] * D_MODEL + sA * 8 : nullptr;
    }

    f32x4 acc[3][4];
    #pragma unroll
    for (int i = 0; i < 3; ++i)
      #pragma unroll
      for (int j = 0; j < 4; ++j) acc[i][j] = (f32x4)0.f;

    uint4 areg[6]; float4 breg[4];

    auto LOAD = [&](int k0) {
      #pragma unroll
      for (int p = 0; p < 6; ++p)
        areg[p] = aptr[p] ? *(const uint4*)(aptr[p] + k0) : make_uint4(0u, 0u, 0u, 0u);
      #pragma unroll
      for (int p = 0; p < 4; ++p)
        breg[p] = *(const float4*)(bptr[p] + k0);
    };
    auto WRITE = [&](int b) {
      unsigned short* A_ = lds + b * BUF;
      unsigned short* B_ = A_ + LDSA;
      #pragma unroll
      for (int p = 0; p < 6; ++p) {
        int pr = p * 32 + rA;
        *(uint4*)(A_ + pr * 64 + (sA ^ (pr & 7)) * 8) = areg[p];
      }
      #pragma unroll
      for (int p = 0; p < 4; ++p) {
        int rr = p * 16 + rB;
        unsigned lo = pk2(breg[p].x, breg[p].y);
        unsigned hi = pk2(breg[p].z, breg[p].w);
        int phys = (qB >> 1) ^ (rr & 7);
        *(uint2*)(B_ + rr * 64 + phys * 8 + (qB & 1) * 4) = make_uint2(lo, hi);
      }
    };
    auto COMPUTE = [&](int b) {
      const unsigned short* A_ = lds + b * BUF;
      const unsigned short* B_ = A_ + LDSA;
      #pragma unroll
      for (int ks = 0; ks < 2; ++ks) {
        short8 a[3], bb[4];
        #pragma unroll
        for (int mi = 0; mi < 3; ++mi)
          a[mi] = *(const short8*)(A_ + arow[mi] * 64 + physA[ks][mi] * 8);
        #pragma unroll
        for (int ni = 0; ni < 4; ++ni)
          bb[ni] = *(const short8*)(B_ + brow[ni] * 64 + physB[ks][ni] * 8);
        #pragma unroll
        for (int mi = 0; mi < 3; ++mi)
          #pragma unroll
          for (int ni = 0; ni < 4; ++ni)
            acc[mi][ni] = __builtin_amdgcn_mfma_f32_16x16x32_bf16(a[mi], bb[ni], acc[mi][ni], 0, 0, 0);
      }
    };

    LOAD(0);
    WRITE(0);
    __syncthreads();
    #pragma unroll 1
    for (int t = 0; t < NK1; ++t) {
      if (t + 1 < NK1) LOAD((t + 1) * 64);
      COMPUTE(t & 1);
      if (t + 1 < NK1) {
        WRITE((t + 1) & 1);
        __syncthreads();
      }
    }

    // epilogue: SiLU * gate -> bf16 hbuf
    const int rsub = (lane >> 4) * 4;
    const int csub = lane & 15;
    #pragma unroll
    for (int mi = 0; mi < 3; ++mi) {
      #pragma unroll
      for (int rg = 0; rg < 4; ++rg) {
        int r = wv * 48 + mi * 16 + rsub + rg;
        if (r < mcnt) {
          float wt = wgt[base + r];
          unsigned short* hrow = hbuf + (long)(base + r) * D_HID + nc * 64 + csub;
          #pragma unroll
          for (int ni = 0; ni < 4; ++ni) {
            float v = acc[mi][ni][rg];
            float sv = v / (1.f + __expf(-v)) * wt;
            hrow[ni * 16] = f2bf(sv);
          }
        }
      }
    }
    __syncthreads();   // protect LDS before next pass
  }
}

__global__ __launch_bounds__(256) void ffn2_kernel(
    const unsigned short* __restrict__ hbuf, const float* __restrict__ W2,
    const int* __restrict__ offs, float* __restrict__ sbuf)
{
  const int e  = blockIdx.x;
  const int nc = blockIdx.y;                  // 0..23 : 64-col chunk of D_MODEL
  const int cnt = offs[e + 1] - offs[e];
  if (cnt == 0) return;

  __shared__ unsigned short lds[2 * BUF];

  const int tid = threadIdx.x;
  const int lane = tid & 63;
  const int wv = tid >> 6;

  const int qB = tid & 15;
  const int rB = tid >> 4;
  const float* bptr[4];
  #pragma unroll
  for (int p = 0; p < 4; ++p)
    bptr[p] = W2 + ((long)e * D_MODEL + nc * 64 + p * 16 + rB) * D_HID + qB * 4;

  const int sA = tid & 7;
  const int rA = tid >> 3;

  int arow[3], brow[4];
  int physA[2][3], physB[2][4];
  #pragma unroll
  for (int mi = 0; mi < 3; ++mi) {
    arow[mi] = wv * 48 + mi * 16 + (lane & 15);
    #pragma unroll
    for (int ks = 0; ks < 2; ++ks)
      physA[ks][mi] = (ks * 4 + (lane >> 4)) ^ (arow[mi] & 7);
  }
  #pragma unroll
  for (int ni = 0; ni < 4; ++ni) {
    brow[ni] = ni * 16 + (lane & 15);
    #pragma unroll
    for (int ks = 0; ks < 2; ++ks)
      physB[ks][ni] = (ks * 4 + (lane >> 4)) ^ (brow[ni] & 7);
  }

  for (int m0 = 0; m0 < cnt; m0 += MT) {
    const int base = offs[e] + m0;
    const int mcnt = min(MT, cnt - m0);

    const unsigned short* aptr[6];
    #pragma unroll
    for (int p = 0; p < 6; ++p) {
      int pr = p * 32 + rA;
      aptr[p] = (pr < mcnt) ? hbuf + (long)(base + pr) * D_HID + sA * 8 : nullptr;
    }

    f32x4 acc[3][4];
    #pragma unroll
    for (int i = 0; i < 3; ++i)
      #pragma unroll
      for (int j = 0; j < 4; ++j) acc[i][j] = (f32x4)0.f;

    uint4 areg[6]; float4 breg[4];

    auto LOAD = [&](int k0) {
      #pragma unroll
      for (int p = 0; p < 6; ++p)
        areg[p] = aptr[p] ? *(const uint4*)(aptr[p] + k0) : make_uint4(0u, 0u, 0u, 0u);
      #pragma unroll
      for (int p = 0; p < 4; ++p)
        breg[p] = *(const float4*)(bptr[p] + k0);
    };
    auto WRITE = [&](int b) {
      unsigned short* A_ = lds + b * BUF;
      unsigned short* B_ = A_ + LDSA;
      #pragma unroll
      for (int p = 0; p < 6; ++p) {
        int pr = p * 32 + rA;
        *(uint4*)(A_ + pr * 64 + (sA ^ (pr & 7)) * 8) = areg[p];
      }
      #pragma unroll
      for (int p = 0; p < 4; ++p) {
        int rr = p * 16 + rB;
        unsigned lo = pk2(breg[p].x, breg[p].y);
        unsigned hi = pk2(breg[p].z, breg[p].w);
        int phys = (qB >> 1) ^ (rr & 7);
        *(uint2*)(B_ + rr * 64 + phys * 8 + (qB & 1) * 4) = make_uint2(lo, hi);
      }
    };
    auto COMPUTE = [&](int b) {
      const unsigned short* A_ = lds + b * BUF;
      const unsigned short* B_ = A_ + LDSA;
      #pragma unroll
      for (int ks = 0; ks < 2; ++ks) {
        short8 a[3], bb[4];
        #pragma unroll
        for (int mi = 0; mi < 3; ++mi)
          a[mi] = *(const short8*)(A_ + arow[mi] * 64 + physA[ks][mi] * 8);
        #pragma unroll
        for (int ni = 0; ni < 4; ++ni)
          bb[ni] = *(const short8*)(B_ + brow[ni] * 64 + physB[ks][ni] * 8);
        #pragma unroll
        for (int mi = 0; mi < 3; ++mi)
          #pragma unroll
          for (int ni = 0; ni < 4; ++ni)
            acc[mi][ni] = __builtin_amdgcn_mfma_f32_16x16x32_bf16(a[mi], bb[ni], acc[mi][ni], 0, 0, 0);
      }
    };

    LOAD(0);
    WRITE(0);
    __syncthreads();
    #pragma unroll 1
    for (int t = 0; t < NK2; ++t) {
      if (t + 1 < NK2) LOAD((t + 1) * 64);
      COMPUTE(t & 1);
      if (t + 1 < NK2) {
        WRITE((t + 1) & 1);
        __syncthreads();
      }
    }

    // epilogue: LDS transpose -> coalesced float4 stores into slot buffer
    __syncthreads();
    float* fds = (float*)lds;
    const int rsub = (lane >> 4) * 4;
    const int csub = lane & 15;
    #pragma unroll
    for (int mi = 0; mi < 3; ++mi) {
      #pragma unroll
      for (int rg = 0; rg < 4; ++rg) {
        int r = wv * 48 + mi * 16 + rsub + rg;
        #pragma unroll
        for (int ni = 0; ni < 4; ++ni)
          fds[r * 64 + ni * 16 + csub] = acc[mi][ni][rg];
      }
    }
    __syncthreads();
    #pragma unroll
    for (int q = 0; q < 12; ++q) {
      int f4 = q * 256 + tid;
      int row = f4 >> 4, c4 = f4 & 15;
      if (row < mcnt)
        *(float4*)(sbuf + (long)(base + row) * D_MODEL + nc * 64 + c4 * 4) =
            *(const float4*)(fds + row * 64 + c4 * 4);
    }
    __syncthreads();   // protect LDS before next pass
  }
}

// ---------------- gather + LayerNorm ----------------

__global__ __launch_bounds__(192) void ln_kernel(const float* __restrict__ sbuf,
    const int* __restrict__ tok2slot, float* __restrict__ out,
    const float* __restrict__ gamma, const float* __restrict__ beta)
{
  const int tid = threadIdx.x;
  const int t = blockIdx.x;
  const long r0 = (long)tok2slot[t * 2]     * D_MODEL;
  const long r1 = (long)tok2slot[t * 2 + 1] * D_MODEL;

  float4 a0 = *(const float4*)(sbuf + r0 + tid * 8);
  float4 a1 = *(const float4*)(sbuf + r0 + tid * 8 + 4);
  float4 b0 = *(const float4*)(sbuf + r1 + tid * 8);
  float4 b1 = *(const float4*)(sbuf + r1 + tid * 8 + 4);
  float4 a = make_float4(a0.x + b0.x, a0.y + b0.y, a0.z + b0.z, a0.w + b0.w);
  float4 b = make_float4(a1.x + b1.x, a1.y + b1.y, a1.z + b1.z, a1.w + b1.w);

  float s  = ((a.x + a.y) + (a.z + a.w)) + ((b.x + b.y) + (b.z + b.w));
  float sq = ((a.x * a.x + a.y * a.y) + (a.z * a.z + a.w * a.w)) +
             ((b.x * b.x + b.y * b.y) + (b.z * b.z + b.w * b.w));
  #pragma unroll
  for (int off = 32; off > 0; off >>= 1) {
    s  += __shfl_xor(s, off);
    sq += __shfl_xor(sq, off);
  }
  __shared__ float ss[3], sqs[3];
  int wv = tid >> 6;
  if ((tid & 63) == 0) { ss[wv] = s; sqs[wv] = sq; }
  __syncthreads();
  s  = ss[0] + ss[1] + ss[2];
  sq = sqs[0] + sqs[1] + sqs[2];
  const float inv = 1.f / (float)D_MODEL;
  float mu  = s * inv;
  float var = sq * inv - mu * mu;
  float rs  = 1.f / sqrtf(var + 1e-5f);
  float4 g1 = *(const float4*)(gamma + tid * 8);
  float4 g2 = *(const float4*)(gamma + tid * 8 + 4);
  float4 b1v = *(const float4*)(beta + tid * 8);
  float4 b2v = *(const float4*)(beta + tid * 8 + 4);
  a.x = (a.x - mu) * rs * g1.x + b1v.x;
  a.y = (a.y - mu) * rs * g1.y + b1v.y;
  a.z = (a.z - mu) * rs * g1.z + b1v.z;
  a.w = (a.w - mu) * rs * g1.w + b1v.w;
  b.x = (b.x - mu) * rs * g2.x + b2v.x;
  b.y = (b.y - mu) * rs * g2.y + b2v.y;
  b.z = (b.z - mu) * rs * g2.z + b2v.z;
  b.w = (b.w - mu) * rs * g2.w + b2v.w;
  float* row = out + (long)t * D_MODEL;
  *(float4*)(row + tid * 8)     = a;
  *(float4*)(row + tid * 8 + 4) = b;
}

// ---------------- launch ----------------

extern "C" void kernel_launch(void* const* d_in, const int* in_sizes, int n_in,
                              void* d_out, int out_size, void* d_ws, size_t ws_size,
                              hipStream_t stream) {
  const float* x     = (const float*)d_in[0];
  const float* Wr    = (const float*)d_in[1];
  const float* W1    = (const float*)d_in[2];
  const float* W2    = (const float*)d_in[3];
  const float* gamma = (const float*)d_in[4];
  const float* beta  = (const float*)d_in[5];
  float* out = (float*)d_out;

  char* ws = (char*)d_ws;
  unsigned short* xb     = (unsigned short*)(ws + 0);          // 12,582,912
  unsigned short* hbuf   = (unsigned short*)(ws + 12582912);   //  8,388,608
  float*          sbuf   = (float*)(ws + 20971520);            // 50,331,648
  int*   topidx   = (int*)  (ws + 71303168);                   // 32,768
  float* topw     = (float*)(ws + 71335936);                   // 32,768
  int*   counts   = (int*)  (ws + 71368704);                   // 256
  int*   cursor   = (int*)  (ws + 71368960);                   // 256
  int*   offs     = (int*)  (ws + 71369216);                   // 512
  int*   tok2slot = (int*)  (ws + 71369728);                   // 32,768
  int*   perm     = (int*)  (ws + 71402496);                   // 32,768
  float* wgt      = (float*)(ws + 71435264);                   // 32,768 -> end 71,468,032

  hipLaunchKernelGGL(zero_small_kernel, dim3(1), dim3(64), 0, stream, counts);
  hipLaunchKernelGGL(cvt_kernel, dim3((NTOK * D_MODEL) / (256 * 8)), dim3(256), 0, stream, x, xb);
  hipLaunchKernelGGL(router_kernel, dim3(NTOK / 8), dim3(256), 0, stream, x, Wr, topidx, topw, counts);
  hipLaunchKernelGGL(scan_kernel, dim3(1), dim3(64), 0, stream, counts, offs, cursor);
  hipLaunchKernelGGL(scatter_kernel, dim3(NTOK / 256), dim3(256), 0, stream, topidx, topw, offs, cursor, perm, wgt, tok2slot);
  hipLaunchKernelGGL(ffn1_kernel, dim3(NEXP, 8), dim3(256), 0, stream, xb, W1, offs, perm, wgt, hbuf);
  hipLaunchKernelGGL(ffn2_kernel, dim3(NEXP, 24), dim3(256), 0, stream, hbuf, W2, offs, sbuf);
  hipLaunchKernelGGL(ln_kernel, dim3(NTOK), dim3(192), 0, stream, sbuf, tok2slot, out, gamma, beta);
}